// Round 1
// baseline (437.210 us; speedup 1.0000x reference)
//
#include <hip/hip_runtime.h>
#include <hip/hip_bf16.h>

// Problem constants
#define NV 8192      // nodes
#define FI 512       // in features
#define HD 256       // hidden
#define LD 64        // latent
#define NE 262144    // edges

typedef __bf16 bf16x8 __attribute__((ext_vector_type(8)));
typedef float f32x4 __attribute__((ext_vector_type(4)));

// ---------------- degree count ----------------
__global__ void k_count(const int* __restrict__ ei, unsigned* __restrict__ deg) {
    int e = blockIdx.x * 256 + threadIdx.x;
    int d = ei[NE + e];
    atomicAdd(&deg[d], 1u);
}

__global__ void k_dinv(const unsigned* __restrict__ deg, float* __restrict__ dinv) {
    int i = blockIdx.x * 256 + threadIdx.x;
    dinv[i] = rsqrtf((float)(deg[i] + 1u));
}

// ---------------- exclusive scan over 8192 counts (single block) ----------------
__global__ void k_scan(const unsigned* __restrict__ cnt, unsigned* __restrict__ offs) {
    __shared__ unsigned sh[256];
    int tid = threadIdx.x;
    int base = tid * 32;
    unsigned local = 0;
    #pragma unroll
    for (int j = 0; j < 32; ++j) local += cnt[base + j];
    sh[tid] = local;
    __syncthreads();
    for (int off = 1; off < 256; off <<= 1) {
        unsigned v = 0;
        if (tid >= off) v = sh[tid - off];
        __syncthreads();
        if (tid >= off) sh[tid] += v;
        __syncthreads();
    }
    unsigned run = sh[tid] - local;   // exclusive base for this thread's chunk
    for (int j = 0; j < 32; ++j) { offs[base + j] = run; run += cnt[base + j]; }
}

// ---------------- scatter edges into CSR buckets ----------------
__global__ void k_scatter(const int* __restrict__ ei, const unsigned* __restrict__ offs,
                          unsigned* __restrict__ cur, const float* __restrict__ dinv,
                          int* __restrict__ srcs, float* __restrict__ normv) {
    int e = blockIdx.x * 256 + threadIdx.x;
    int s = ei[e], d = ei[NE + e];
    unsigned p = offs[d] + atomicAdd(&cur[d], 1u);
    srcs[p] = s;
    normv[p] = dinv[s] * dinv[d];
}

// ---------------- fp32 -> bf16 hi/lo split (elementwise) ----------------
__global__ void k_split(const float* __restrict__ in, __bf16* __restrict__ hi,
                        __bf16* __restrict__ lo, int n) {
    int i = blockIdx.x * 256 + threadIdx.x;
    if (i < n) {
        float v = in[i];
        __bf16 h = (__bf16)v;
        hi[i] = h;
        lo[i] = (__bf16)(v - (float)h);
    }
}

// transpose-split W1 [FI][HD] -> W1t [HD][FI]
__global__ void k_w1t_split(const float* __restrict__ W1, __bf16* __restrict__ hi,
                            __bf16* __restrict__ lo) {
    int idx = blockIdx.x * 256 + threadIdx.x;  // over HD*FI
    int h = idx >> 9, f = idx & (FI - 1);
    float v = W1[f * HD + h];
    __bf16 hh = (__bf16)v;
    hi[idx] = hh;
    lo[idx] = (__bf16)(v - (float)hh);
}

// concat-transpose-split Wmu,Wsig [HD][LD] -> Wcat^T [2*LD][HD]
__global__ void k_wcat_split(const float* __restrict__ Wmu, const float* __restrict__ Wsig,
                             __bf16* __restrict__ hi, __bf16* __restrict__ lo) {
    int idx = blockIdx.x * 256 + threadIdx.x;  // over 128*HD
    int r = idx >> 8, k = idx & (HD - 1);
    float v = (r < LD) ? Wmu[k * LD + r] : Wsig[k * LD + (r - LD)];
    __bf16 hh = (__bf16)v;
    hi[idx] = hh;
    lo[idx] = (__bf16)(v - (float)hh);
}

// ---------------- split-bf16 MFMA GEMM:  C[M][NN_] = A[M][K] * Bt[NN_][K]^T ----------------
// one wave per 16(m) x 64(n) tile; A,B split hi/lo (3 MFMAs per tile per k-step)
template<int K, int NN_>
__global__ void k_gemm_split(const __bf16* __restrict__ Ah, const __bf16* __restrict__ Al,
                             const __bf16* __restrict__ Bh, const __bf16* __restrict__ Bl,
                             float* __restrict__ C) {
    int lane = threadIdx.x;            // 64 threads
    int mi = blockIdx.x * 16, nj = blockIdx.y * 64;
    int la = lane & 15, kq = (lane >> 4) * 8;
    size_t arow = (size_t)(mi + la) * K + kq;
    f32x4 acc[4];
    #pragma unroll
    for (int t = 0; t < 4; ++t) acc[t] = (f32x4){0.f, 0.f, 0.f, 0.f};
    for (int k0 = 0; k0 < K; k0 += 32) {
        bf16x8 ah = *(const bf16x8*)(Ah + arow + k0);
        bf16x8 al = *(const bf16x8*)(Al + arow + k0);
        #pragma unroll
        for (int t = 0; t < 4; ++t) {
            size_t brow = (size_t)(nj + t * 16 + la) * K + kq + k0;
            bf16x8 bh = *(const bf16x8*)(Bh + brow);
            bf16x8 bl = *(const bf16x8*)(Bl + brow);
            acc[t] = __builtin_amdgcn_mfma_f32_16x16x32_bf16(ah, bh, acc[t], 0, 0, 0);
            acc[t] = __builtin_amdgcn_mfma_f32_16x16x32_bf16(ah, bl, acc[t], 0, 0, 0);
            acc[t] = __builtin_amdgcn_mfma_f32_16x16x32_bf16(al, bh, acc[t], 0, 0, 0);
        }
    }
    int rq = (lane >> 4) * 4;
    #pragma unroll
    for (int t = 0; t < 4; ++t)
        #pragma unroll
        for (int r = 0; r < 4; ++r)
            C[(size_t)(mi + rq + r) * NN_ + nj + t * 16 + la] = acc[t][r];
}

// ---------------- GCN aggregation layer 1: h = relu(agg(xw) + b1), write bf16 hi/lo ----------------
__global__ void k_agg1(const float* __restrict__ xw, const float* __restrict__ dinv,
                       const unsigned* __restrict__ offs, const unsigned* __restrict__ deg,
                       const int* __restrict__ srcs, const float* __restrict__ normv,
                       const float* __restrict__ b1, __bf16* __restrict__ hbh,
                       __bf16* __restrict__ hbl) {
    __shared__ int s_src[256];
    __shared__ float s_nrm[256];
    int d = blockIdx.x, f = threadIdx.x;  // 256 threads = HD features
    float di = dinv[d];
    unsigned st = offs[d], cnt = deg[d];
    float s = xw[(size_t)d * HD + f] * di * di;   // self-loop
    for (unsigned b = 0; b < cnt; b += 256) {
        int nb = (int)min(256u, cnt - b);
        if (f < nb) { s_src[f] = srcs[st + b + f]; s_nrm[f] = normv[st + b + f]; }
        __syncthreads();
        for (int e = 0; e < nb; ++e)
            s += xw[(size_t)s_src[e] * HD + f] * s_nrm[e];
        __syncthreads();
    }
    s += b1[f];
    s = fmaxf(s, 0.f);
    __bf16 h = (__bf16)s;
    size_t o = (size_t)d * HD + f;
    hbh[o] = h;
    hbl[o] = (__bf16)(s - (float)h);
}

// ---------------- layer-2 aggregation (both heads) + decode z = gnoise*exp(xu)+xs ----------------
__global__ void k_agg2(const float* __restrict__ hw, const float* __restrict__ dinv,
                       const unsigned* __restrict__ offs, const unsigned* __restrict__ deg,
                       const int* __restrict__ srcs, const float* __restrict__ normv,
                       const float* __restrict__ bmu, const float* __restrict__ bsig,
                       const float* __restrict__ gno, __bf16* __restrict__ zh,
                       __bf16* __restrict__ zl) {
    __shared__ int s_src[128];
    __shared__ float s_nrm[128];
    __shared__ float sg[128];
    int d = blockIdx.x, f = threadIdx.x;  // 128 threads: cols 0-63 mu, 64-127 sig
    float di = dinv[d];
    unsigned st = offs[d], cnt = deg[d];
    float s = hw[(size_t)d * 128 + f] * di * di;
    for (unsigned b = 0; b < cnt; b += 128) {
        int nb = (int)min(128u, cnt - b);
        if (f < nb) { s_src[f] = srcs[st + b + f]; s_nrm[f] = normv[st + b + f]; }
        __syncthreads();
        for (int e = 0; e < nb; ++e)
            s += hw[(size_t)s_src[e] * 128 + f] * s_nrm[e];
        __syncthreads();
    }
    s += (f < LD) ? bmu[f] : bsig[f - LD];
    sg[f] = s;
    __syncthreads();
    if (f < LD) {
        float xu = sg[f], xs = sg[LD + f];
        float z = gno[(size_t)d * LD + f] * __expf(xu) + xs;
        __bf16 h = (__bf16)z;
        size_t o = (size_t)d * LD + f;
        zh[o] = h;
        zl[o] = (__bf16)(z - (float)h);
    }
}

// ---------------- out = sigmoid(Z Z^T), split-bf16 MFMA, 128x128 tile per block ----------------
__launch_bounds__(256)
__global__ void k_zzt(const __bf16* __restrict__ Zh, const __bf16* __restrict__ Zl,
                      float* __restrict__ out) {
    // pad rows to 72 bf16 (144 B): quad lanes land 2-way per bank = free
    __shared__ __bf16 zih[128][72], zil[128][72], zjh[128][72], zjl[128][72];
    int tid = threadIdx.x;
    int bi = blockIdx.x * 128, bj = blockIdx.y * 128;
    #pragma unroll
    for (int it = 0; it < 4; ++it) {
        int c = it * 256 + tid;
        int row = c >> 3, col = (c & 7) * 8;
        *(bf16x8*)&zih[row][col] = *(const bf16x8*)(Zh + (size_t)(bi + row) * LD + col);
        *(bf16x8*)&zil[row][col] = *(const bf16x8*)(Zl + (size_t)(bi + row) * LD + col);
        *(bf16x8*)&zjh[row][col] = *(const bf16x8*)(Zh + (size_t)(bj + row) * LD + col);
        *(bf16x8*)&zjl[row][col] = *(const bf16x8*)(Zl + (size_t)(bj + row) * LD + col);
    }
    __syncthreads();
    int wv = tid >> 6, lane = tid & 63;
    int m0 = wv * 32;                    // each wave: 32 rows x 128 cols
    int la = lane & 15, kq = (lane >> 4) * 8;
    f32x4 acc[2][8];
    #pragma unroll
    for (int s = 0; s < 2; ++s)
        #pragma unroll
        for (int t = 0; t < 8; ++t) acc[s][t] = (f32x4){0.f, 0.f, 0.f, 0.f};
    #pragma unroll
    for (int k0 = 0; k0 < LD; k0 += 32) {
        bf16x8 ah0 = *(const bf16x8*)&zih[m0 + la][k0 + kq];
        bf16x8 ah1 = *(const bf16x8*)&zih[m0 + 16 + la][k0 + kq];
        bf16x8 al0 = *(const bf16x8*)&zil[m0 + la][k0 + kq];
        bf16x8 al1 = *(const bf16x8*)&zil[m0 + 16 + la][k0 + kq];
        #pragma unroll
        for (int t = 0; t < 8; ++t) {
            bf16x8 bh = *(const bf16x8*)&zjh[t * 16 + la][k0 + kq];
            bf16x8 bl = *(const bf16x8*)&zjl[t * 16 + la][k0 + kq];
            acc[0][t] = __builtin_amdgcn_mfma_f32_16x16x32_bf16(ah0, bh, acc[0][t], 0, 0, 0);
            acc[0][t] = __builtin_amdgcn_mfma_f32_16x16x32_bf16(ah0, bl, acc[0][t], 0, 0, 0);
            acc[0][t] = __builtin_amdgcn_mfma_f32_16x16x32_bf16(al0, bh, acc[0][t], 0, 0, 0);
            acc[1][t] = __builtin_amdgcn_mfma_f32_16x16x32_bf16(ah1, bh, acc[1][t], 0, 0, 0);
            acc[1][t] = __builtin_amdgcn_mfma_f32_16x16x32_bf16(ah1, bl, acc[1][t], 0, 0, 0);
            acc[1][t] = __builtin_amdgcn_mfma_f32_16x16x32_bf16(al1, bh, acc[1][t], 0, 0, 0);
        }
    }
    int rq = (lane >> 4) * 4;
    #pragma unroll
    for (int s = 0; s < 2; ++s)
        #pragma unroll
        for (int t = 0; t < 8; ++t)
            #pragma unroll
            for (int r = 0; r < 4; ++r) {
                int row = bi + m0 + s * 16 + rq + r;
                int col = bj + t * 16 + la;
                float v = acc[s][t][r];
                out[(size_t)row * NV + col] = __builtin_amdgcn_rcpf(1.f + __expf(-v));
            }
}

extern "C" void kernel_launch(void* const* d_in, const int* in_sizes, int n_in,
                              void* d_out, int out_size, void* d_ws, size_t ws_size,
                              hipStream_t stream) {
    const float* x    = (const float*)d_in[0];
    const int*   ei   = (const int*)d_in[1];
    const float* W1   = (const float*)d_in[2];
    const float* b1   = (const float*)d_in[3];
    const float* Wmu  = (const float*)d_in[4];
    const float* bmu  = (const float*)d_in[5];
    const float* Wsig = (const float*)d_in[6];
    const float* bsig = (const float*)d_in[7];
    const float* gno  = (const float*)d_in[8];
    float* out = (float*)d_out;
    char* ws = (char*)d_ws;

    // workspace layout (bytes)
    unsigned* deg   = (unsigned*)(ws + 0);               // 32 KB
    unsigned* cur   = (unsigned*)(ws + 32768);           // 32 KB
    unsigned* offs  = (unsigned*)(ws + 65536);           // 32 KB
    float*    dinv  = (float*)   (ws + 98304);           // 32 KB
    int*      srcs  = (int*)     (ws + 131072);          // 1 MB
    float*    normv = (float*)   (ws + 1179648);         // 1 MB
    __bf16*   w1th  = (__bf16*)  (ws + 2228224);         // 256 KB
    __bf16*   w1tl  = (__bf16*)  (ws + 2490368);         // 256 KB
    __bf16*   wch   = (__bf16*)  (ws + 2752512);         // 64 KB
    __bf16*   wcl   = (__bf16*)  (ws + 2818048);         // 64 KB
    char*     bufA  = ws + 2883584;                      // 16 MB
    char*     bufB  = ws + 19660800;                     // 8 MB
    // phase-1 aliases
    __bf16* xh = (__bf16*)(bufA);                        // 8 MB
    __bf16* xl = (__bf16*)(bufA + 8388608);              // 8 MB
    float*  xw = (float*)(bufB);                         // 8 MB
    // phase-2 aliases (xh/xl dead after GEMM1)
    __bf16* hbh = (__bf16*)(bufA);                       // 4 MB
    __bf16* hbl = (__bf16*)(bufA + 4194304);             // 4 MB
    float*  hw  = (float*)(bufA + 8388608);              // 4 MB
    // phase-3 aliases (xw dead after agg1)
    __bf16* zh = (__bf16*)(bufB);                        // 1 MB
    __bf16* zl = (__bf16*)(bufB + 1048576);              // 1 MB

    // 1) zero deg + cursor
    hipMemsetAsync(ws, 0, 65536, stream);
    // 2) CSR build
    k_count<<<NE / 256, 256, 0, stream>>>(ei, deg);
    k_dinv<<<NV / 256, 256, 0, stream>>>(deg, dinv);
    k_scan<<<1, 256, 0, stream>>>(deg, offs);
    k_scatter<<<NE / 256, 256, 0, stream>>>(ei, offs, cur, dinv, srcs, normv);
    // 3) input conversions
    k_split<<<(NV * FI) / 256, 256, 0, stream>>>(x, xh, xl, NV * FI);
    k_w1t_split<<<(HD * FI) / 256, 256, 0, stream>>>(W1, w1th, w1tl);
    k_wcat_split<<<(128 * HD) / 256, 256, 0, stream>>>(Wmu, Wsig, wch, wcl);
    // 4) xw = x @ W1   [8192,512]x[512,256]
    k_gemm_split<FI, HD><<<dim3(NV / 16, HD / 64), 64, 0, stream>>>(xh, xl, w1th, w1tl, xw);
    // 5) h = relu(agg(xw)+b1) -> bf16 hi/lo
    k_agg1<<<NV, HD, 0, stream>>>(xw, dinv, offs, deg, srcs, normv, b1, hbh, hbl);
    // 6) hw = h @ [Wmu|Wsig]   [8192,256]x[256,128]
    k_gemm_split<HD, 128><<<dim3(NV / 16, 128 / 64), 64, 0, stream>>>(hbh, hbl, wch, wcl, hw);
    // 7) aggregate heads + decode z
    k_agg2<<<NV, 128, 0, stream>>>(hw, dinv, offs, deg, srcs, normv, bmu, bsig, gno, zh, zl);
    // 8) out = sigmoid(z z^T)
    k_zzt<<<dim3(NV / 128, NV / 128), 256, 0, stream>>>(zh, zl, out);
}

// Round 2
// 432.807 us; speedup vs baseline: 1.0102x; 1.0102x over previous
//
#include <hip/hip_runtime.h>
#include <hip/hip_bf16.h>

// Problem constants
#define NV 8192      // nodes
#define FI 512       // in features
#define HD 256       // hidden
#define LD 64        // latent
#define NE 262144    // edges

typedef __bf16 bf16x8 __attribute__((ext_vector_type(8)));
typedef float f32x4 __attribute__((ext_vector_type(4)));

// ---------------- fused prep: hi/lo splits of x, W1^T, [Wmu|Wsig]^T + zero deg/cur ----------------
__global__ void k_prep(const float* __restrict__ x, const float* __restrict__ W1,
                       const float* __restrict__ Wmu, const float* __restrict__ Wsig,
                       __bf16* __restrict__ xh, __bf16* __restrict__ xl,
                       __bf16* __restrict__ w1th, __bf16* __restrict__ w1tl,
                       __bf16* __restrict__ wch, __bf16* __restrict__ wcl,
                       unsigned* __restrict__ deg, unsigned* __restrict__ cur) {
    int idx = blockIdx.x * 256 + threadIdx.x;
    if (idx < 2 * NV) {  // zero degree + cursor arrays (k_count runs in a later dispatch)
        if (idx < NV) deg[idx] = 0u; else cur[idx - NV] = 0u;
    }
    if (idx < NV * FI) {
        float v = x[idx];
        __bf16 h = (__bf16)v;
        xh[idx] = h;
        xl[idx] = (__bf16)(v - (float)h);
    } else if (idx < NV * FI + HD * FI) {
        int j = idx - NV * FI;           // W1 [FI][HD] -> W1t [HD][FI]
        int h = j >> 9, f = j & (FI - 1);
        float v = W1[f * HD + h];
        __bf16 b = (__bf16)v;
        w1th[j] = b;
        w1tl[j] = (__bf16)(v - (float)b);
    } else if (idx < NV * FI + HD * FI + 128 * HD) {
        int j = idx - NV * FI - HD * FI; // [Wmu|Wsig] -> Wcat^T [128][HD]
        int r = j >> 8, k = j & (HD - 1);
        float v = (r < LD) ? Wmu[k * LD + r] : Wsig[k * LD + (r - LD)];
        __bf16 b = (__bf16)v;
        wch[j] = b;
        wcl[j] = (__bf16)(v - (float)b);
    }
}

// ---------------- degree count ----------------
__global__ void k_count(const int* __restrict__ ei, unsigned* __restrict__ deg) {
    int e = blockIdx.x * 256 + threadIdx.x;
    int d = ei[NE + e];
    atomicAdd(&deg[d], 1u);
}

// ---------------- exclusive scan over 8192 counts (single block) + dinv ----------------
__global__ void k_scan(const unsigned* __restrict__ cnt, unsigned* __restrict__ offs,
                       float* __restrict__ dinv) {
    __shared__ unsigned sh[256];
    int tid = threadIdx.x;
    int base = tid * 32;
    unsigned c[32];
    unsigned local = 0;
    #pragma unroll
    for (int j = 0; j < 32; ++j) { c[j] = cnt[base + j]; local += c[j]; }
    sh[tid] = local;
    __syncthreads();
    for (int off = 1; off < 256; off <<= 1) {
        unsigned v = 0;
        if (tid >= off) v = sh[tid - off];
        __syncthreads();
        if (tid >= off) sh[tid] += v;
        __syncthreads();
    }
    unsigned run = sh[tid] - local;   // exclusive base for this thread's chunk
    #pragma unroll
    for (int j = 0; j < 32; ++j) {
        offs[base + j] = run;
        dinv[base + j] = rsqrtf((float)(c[j] + 1u));
        run += c[j];
    }
}

// ---------------- scatter edges into CSR buckets ----------------
__global__ void k_scatter(const int* __restrict__ ei, const unsigned* __restrict__ offs,
                          unsigned* __restrict__ cur, const float* __restrict__ dinv,
                          int* __restrict__ srcs, float* __restrict__ normv) {
    int e = blockIdx.x * 256 + threadIdx.x;
    int s = ei[e], d = ei[NE + e];
    unsigned p = offs[d] + atomicAdd(&cur[d], 1u);
    srcs[p] = s;
    normv[p] = dinv[s] * dinv[d];
}

// ---------------- split-bf16 MFMA GEMM:  C[M][NN_] = A[M][K] * Bt[NN_][K]^T, bf16 out ----------------
// one wave per 16(m) x 64(n) tile; A,B split hi/lo (3 MFMAs per tile per k-step)
template<int K, int NN_>
__global__ void k_gemm_split(const __bf16* __restrict__ Ah, const __bf16* __restrict__ Al,
                             const __bf16* __restrict__ Bh, const __bf16* __restrict__ Bl,
                             __bf16* __restrict__ C) {
    int lane = threadIdx.x;            // 64 threads
    int mi = blockIdx.x * 16, nj = blockIdx.y * 64;
    int la = lane & 15, kq = (lane >> 4) * 8;
    size_t arow = (size_t)(mi + la) * K + kq;
    f32x4 acc[4];
    #pragma unroll
    for (int t = 0; t < 4; ++t) acc[t] = (f32x4){0.f, 0.f, 0.f, 0.f};
    for (int k0 = 0; k0 < K; k0 += 32) {
        bf16x8 ah = *(const bf16x8*)(Ah + arow + k0);
        bf16x8 al = *(const bf16x8*)(Al + arow + k0);
        #pragma unroll
        for (int t = 0; t < 4; ++t) {
            size_t brow = (size_t)(nj + t * 16 + la) * K + kq + k0;
            bf16x8 bh = *(const bf16x8*)(Bh + brow);
            bf16x8 bl = *(const bf16x8*)(Bl + brow);
            acc[t] = __builtin_amdgcn_mfma_f32_16x16x32_bf16(ah, bh, acc[t], 0, 0, 0);
            acc[t] = __builtin_amdgcn_mfma_f32_16x16x32_bf16(ah, bl, acc[t], 0, 0, 0);
            acc[t] = __builtin_amdgcn_mfma_f32_16x16x32_bf16(al, bh, acc[t], 0, 0, 0);
        }
    }
    int rq = (lane >> 4) * 4;
    #pragma unroll
    for (int t = 0; t < 4; ++t)
        #pragma unroll
        for (int r = 0; r < 4; ++r)
            C[(size_t)(mi + rq + r) * NN_ + nj + t * 16 + la] = (__bf16)acc[t][r];
}

// ---------------- GCN aggregation layer 1: h = relu(agg(xw) + b1), write bf16 hi/lo ----------------
__global__ void k_agg1(const __bf16* __restrict__ xwb, const float* __restrict__ dinv,
                       const unsigned* __restrict__ offs, const unsigned* __restrict__ deg,
                       const int* __restrict__ srcs, const float* __restrict__ normv,
                       const float* __restrict__ b1, __bf16* __restrict__ hbh,
                       __bf16* __restrict__ hbl) {
    __shared__ int s_src[256];
    __shared__ float s_nrm[256];
    int d = blockIdx.x, f = threadIdx.x;  // 256 threads = HD features
    float di = dinv[d];
    unsigned st = offs[d], cnt = deg[d];
    float s = (float)xwb[(size_t)d * HD + f] * di * di;   // self-loop
    for (unsigned b = 0; b < cnt; b += 256) {
        int nb = (int)min(256u, cnt - b);
        if (f < nb) { s_src[f] = srcs[st + b + f]; s_nrm[f] = normv[st + b + f]; }
        __syncthreads();
        for (int e = 0; e < nb; ++e)
            s += (float)xwb[(size_t)s_src[e] * HD + f] * s_nrm[e];
        __syncthreads();
    }
    s += b1[f];
    s = fmaxf(s, 0.f);
    __bf16 h = (__bf16)s;
    size_t o = (size_t)d * HD + f;
    hbh[o] = h;
    hbl[o] = (__bf16)(s - (float)h);
}

// ---------------- layer-2 aggregation (both heads) + decode z = gnoise*exp(xu)+xs ----------------
__global__ void k_agg2(const __bf16* __restrict__ hwb, const float* __restrict__ dinv,
                       const unsigned* __restrict__ offs, const unsigned* __restrict__ deg,
                       const int* __restrict__ srcs, const float* __restrict__ normv,
                       const float* __restrict__ bmu, const float* __restrict__ bsig,
                       const float* __restrict__ gno, __bf16* __restrict__ zh,
                       __bf16* __restrict__ zl) {
    __shared__ int s_src[128];
    __shared__ float s_nrm[128];
    __shared__ float sg[128];
    int d = blockIdx.x, f = threadIdx.x;  // 128 threads: cols 0-63 mu, 64-127 sig
    float di = dinv[d];
    unsigned st = offs[d], cnt = deg[d];
    float s = (float)hwb[(size_t)d * 128 + f] * di * di;
    for (unsigned b = 0; b < cnt; b += 128) {
        int nb = (int)min(128u, cnt - b);
        if (f < nb) { s_src[f] = srcs[st + b + f]; s_nrm[f] = normv[st + b + f]; }
        __syncthreads();
        for (int e = 0; e < nb; ++e)
            s += (float)hwb[(size_t)s_src[e] * 128 + f] * s_nrm[e];
        __syncthreads();
    }
    s += (f < LD) ? bmu[f] : bsig[f - LD];
    sg[f] = s;
    __syncthreads();
    if (f < LD) {
        float xu = sg[f], xs = sg[LD + f];
        float z = gno[(size_t)d * LD + f] * __expf(xu) + xs;
        __bf16 h = (__bf16)z;
        size_t o = (size_t)d * LD + f;
        zh[o] = h;
        zl[o] = (__bf16)(z - (float)h);
    }
}

// ---------------- out = sigmoid(Z Z^T), split-bf16 MFMA, 128x128 tile per block ----------------
// B-side (zj) staged in LDS (36 KB -> ~4 blocks/CU); A-side read direct from L2-resident Z.
__launch_bounds__(256)
__global__ void k_zzt(const __bf16* __restrict__ Zh, const __bf16* __restrict__ Zl,
                      float* __restrict__ out) {
    __shared__ __bf16 zjh[128][72], zjl[128][72];  // pad 64->72: quad stride 4 banks, 2-way = free
    int tid = threadIdx.x;
    int bi = blockIdx.x * 128, bj = blockIdx.y * 128;
    #pragma unroll
    for (int it = 0; it < 4; ++it) {
        int c = it * 256 + tid;
        int row = c >> 3, col = (c & 7) * 8;
        *(bf16x8*)&zjh[row][col] = *(const bf16x8*)(Zh + (size_t)(bj + row) * LD + col);
        *(bf16x8*)&zjl[row][col] = *(const bf16x8*)(Zl + (size_t)(bj + row) * LD + col);
    }
    __syncthreads();
    int wv = tid >> 6, lane = tid & 63;
    int m0 = wv * 32;                    // each wave: 32 rows x 128 cols
    int la = lane & 15, kq = (lane >> 4) * 8;
    f32x4 acc[2][8];
    #pragma unroll
    for (int s = 0; s < 2; ++s)
        #pragma unroll
        for (int t = 0; t < 8; ++t) acc[s][t] = (f32x4){0.f, 0.f, 0.f, 0.f};
    #pragma unroll
    for (int k0 = 0; k0 < LD; k0 += 32) {
        size_t r0 = (size_t)(bi + m0 + la) * LD + k0 + kq;
        size_t r1 = (size_t)(bi + m0 + 16 + la) * LD + k0 + kq;
        bf16x8 ah0 = *(const bf16x8*)(Zh + r0);
        bf16x8 al0 = *(const bf16x8*)(Zl + r0);
        bf16x8 ah1 = *(const bf16x8*)(Zh + r1);
        bf16x8 al1 = *(const bf16x8*)(Zl + r1);
        #pragma unroll
        for (int t = 0; t < 8; ++t) {
            bf16x8 bh = *(const bf16x8*)&zjh[t * 16 + la][k0 + kq];
            bf16x8 bl = *(const bf16x8*)&zjl[t * 16 + la][k0 + kq];
            acc[0][t] = __builtin_amdgcn_mfma_f32_16x16x32_bf16(ah0, bh, acc[0][t], 0, 0, 0);
            acc[0][t] = __builtin_amdgcn_mfma_f32_16x16x32_bf16(ah0, bl, acc[0][t], 0, 0, 0);
            acc[0][t] = __builtin_amdgcn_mfma_f32_16x16x32_bf16(al0, bh, acc[0][t], 0, 0, 0);
            acc[1][t] = __builtin_amdgcn_mfma_f32_16x16x32_bf16(ah1, bh, acc[1][t], 0, 0, 0);
            acc[1][t] = __builtin_amdgcn_mfma_f32_16x16x32_bf16(ah1, bl, acc[1][t], 0, 0, 0);
            acc[1][t] = __builtin_amdgcn_mfma_f32_16x16x32_bf16(al1, bh, acc[1][t], 0, 0, 0);
        }
    }
    int rq = (lane >> 4) * 4;
    #pragma unroll
    for (int s = 0; s < 2; ++s)
        #pragma unroll
        for (int t = 0; t < 8; ++t)
            #pragma unroll
            for (int r = 0; r < 4; ++r) {
                int row = bi + m0 + s * 16 + rq + r;
                int col = bj + t * 16 + la;
                float v = acc[s][t][r];
                out[(size_t)row * NV + col] = __builtin_amdgcn_rcpf(1.f + __expf(-v));
            }
}

extern "C" void kernel_launch(void* const* d_in, const int* in_sizes, int n_in,
                              void* d_out, int out_size, void* d_ws, size_t ws_size,
                              hipStream_t stream) {
    const float* x    = (const float*)d_in[0];
    const int*   ei   = (const int*)d_in[1];
    const float* W1   = (const float*)d_in[2];
    const float* b1   = (const float*)d_in[3];
    const float* Wmu  = (const float*)d_in[4];
    const float* bmu  = (const float*)d_in[5];
    const float* Wsig = (const float*)d_in[6];
    const float* bsig = (const float*)d_in[7];
    const float* gno  = (const float*)d_in[8];
    float* out = (float*)d_out;
    char* ws = (char*)d_ws;

    // workspace layout (bytes)
    unsigned* deg   = (unsigned*)(ws + 0);               // 32 KB
    unsigned* cur   = (unsigned*)(ws + 32768);           // 32 KB
    unsigned* offs  = (unsigned*)(ws + 65536);           // 32 KB
    float*    dinv  = (float*)   (ws + 98304);           // 32 KB
    int*      srcs  = (int*)     (ws + 131072);          // 1 MB
    float*    normv = (float*)   (ws + 1179648);         // 1 MB
    __bf16*   w1th  = (__bf16*)  (ws + 2228224);         // 256 KB
    __bf16*   w1tl  = (__bf16*)  (ws + 2490368);         // 256 KB
    __bf16*   wch   = (__bf16*)  (ws + 2752512);         // 64 KB
    __bf16*   wcl   = (__bf16*)  (ws + 2818048);         // 64 KB
    char*     bufA  = ws + 2883584;                      // 16 MB
    char*     bufB  = ws + 19660800;                     // 4 MB
    // phase-1 aliases
    __bf16* xh  = (__bf16*)(bufA);                       // 8 MB
    __bf16* xl  = (__bf16*)(bufA + 8388608);             // 8 MB
    __bf16* xwb = (__bf16*)(bufB);                       // 4 MB  [NV][HD] bf16
    // phase-2 aliases (xh/xl dead after GEMM1)
    __bf16* hbh = (__bf16*)(bufA);                       // 4 MB
    __bf16* hbl = (__bf16*)(bufA + 4194304);             // 4 MB
    __bf16* hwb = (__bf16*)(bufA + 8388608);             // 2 MB  [NV][128] bf16
    // phase-3 aliases (xwb dead after agg1)
    __bf16* zh = (__bf16*)(bufB);                        // 1 MB
    __bf16* zl = (__bf16*)(bufB + 1048576);              // 1 MB

    // 1) fused prep (splits + zero deg/cur)
    const int prep_elems = NV * FI + HD * FI + 128 * HD;  // 4,358,144
    k_prep<<<prep_elems / 256, 256, 0, stream>>>(x, W1, Wmu, Wsig, xh, xl, w1th, w1tl,
                                                 wch, wcl, deg, cur);
    // 2) CSR build
    k_count<<<NE / 256, 256, 0, stream>>>(ei, deg);
    k_scan<<<1, 256, 0, stream>>>(deg, offs, dinv);
    k_scatter<<<NE / 256, 256, 0, stream>>>(ei, offs, cur, dinv, srcs, normv);
    // 3) xw = x @ W1   [8192,512]x[512,256] -> bf16
    k_gemm_split<FI, HD><<<dim3(NV / 16, HD / 64), 64, 0, stream>>>(xh, xl, w1th, w1tl, xwb);
    // 4) h = relu(agg(xw)+b1) -> bf16 hi/lo
    k_agg1<<<NV, HD, 0, stream>>>(xwb, dinv, offs, deg, srcs, normv, b1, hbh, hbl);
    // 5) hw = h @ [Wmu|Wsig]   [8192,256]x[256,128] -> bf16
    k_gemm_split<HD, 128><<<dim3(NV / 16, 128 / 64), 64, 0, stream>>>(hbh, hbl, wch, wcl, hwb);
    // 6) aggregate heads + decode z
    k_agg2<<<NV, 128, 0, stream>>>(hwb, dinv, offs, deg, srcs, normv, bmu, bsig, gno, zh, zl);
    // 7) out = sigmoid(z z^T)
    k_zzt<<<dim3(NV / 128, NV / 128), 256, 0, stream>>>(zh, zl, out);
}